// Round 5
// baseline (393.389 us; speedup 1.0000x reference)
//
#include <hip/hip_runtime.h>
#include <hip/hip_bf16.h>

#define W512   512
#define PATCH  32
#define NP     16        // patches per side
#define L      256       // patches per image
#define NCH    128       // descriptor channels
#define PLANE  (W512 * W512)
#define NSTRIP 128       // 8 batches * 16 strips

typedef float  f32x4 __attribute__((ext_vector_type(4)));
typedef unsigned short u16x4 __attribute__((ext_vector_type(4)));

__device__ __forceinline__ unsigned short f2bf(float f) {
    __hip_bfloat16 h = __float2bfloat16(f);
    return *reinterpret_cast<unsigned short*>(&h);
}
__device__ __forceinline__ float bf2f(unsigned short u) {
    return __uint_as_float(((unsigned int)u) << 16);
}
__device__ __forceinline__ float wave_max(float v) {
    #pragma unroll
    for (int o = 32; o; o >>= 1) v = fmaxf(v, __shfl_xor(v, o, 64));
    return v;
}
__device__ __forceinline__ float wave_sum(float v) {
    #pragma unroll
    for (int o = 32; o; o >>= 1) v += __shfl_xor(v, o, 64);
    return v;
}

// One block = (channel-group cg, strip s). Phase A: this block computes the
// softmax att for patch (s, wp=cg) — bijective, each patch done once — plus
// that patch's coords/score outputs. The 16 producers of strip s ARE its 16
// consumers (bid ≡ s mod 128 -> all on XCD s%8), so attws handoff is
// same-XCD L2. Phase B: R3's strip-sequential pooling of 8 channels.
__global__ __launch_bounds__(256, 8)   // 8 blocks/CU -> all 2048 co-resident
void fused_kernel(const float* __restrict__ det,
                  const float* __restrict__ wsc,
                  const float* __restrict__ desc,
                  float* __restrict__ out,
                  unsigned short* __restrict__ attws,
                  unsigned int* __restrict__ flags) {
    __shared__ float red[12];

    const int bid  = blockIdx.x;
    const int cg   = bid >> 7;       // channel group AND patch-within-strip
    const int s    = bid & 127;      // strip = b*16 + hp
    const int b    = s >> 4;
    const int hp   = s & 15;

    const int t    = threadIdx.x;
    const int wave = t >> 6;
    const int lane = t & 63;

    // ---------- Phase A: softmax att + coords + score for patch (b,hp,cg) ----------
    {
        const int wp  = cg;
        const int r   = t >> 3;          // row within patch
        const int q   = t & 7;           // float4 index within row
        const int row = hp * PATCH + r;
        const int col = wp * PATCH + q * 4;
        const size_t pix = (size_t)b * PLANE + (size_t)row * W512 + col;

        const f32x4 d4 = __builtin_nontemporal_load((const f32x4*)(det + pix));

        float m = fmaxf(fmaxf(d4.x, d4.y), fmaxf(d4.z, d4.w));
        m = wave_max(m);
        if (lane == 0) red[wave] = m;
        __syncthreads();
        m = fmaxf(fmaxf(red[0], red[1]), fmaxf(red[2], red[3]));

        float e0 = expf(d4.x - m);
        float e1 = expf(d4.y - m);
        float e2 = expf(d4.z - m);
        float e3 = expf(d4.w - m);

        float ssum = wave_sum(e0 + e1 + e2 + e3);
        if (lane == 0) red[4 + wave] = ssum;
        __syncthreads();
        ssum = red[4] + red[5] + red[6] + red[7];
        const float inv = 1.0f / ssum;
        e0 *= inv; e1 *= inv; e2 *= inv; e3 *= inv;

        // normalized attention, bf16, image layout
        u16x4 pk;
        pk.x = f2bf(e0); pk.y = f2bf(e1); pk.z = f2bf(e2); pk.w = f2bf(e3);
        *(u16x4*)(attws + pix) = pk;

        const f32x4 w4 = __builtin_nontemporal_load((const f32x4*)(wsc + pix));
        float pu = e0 * (float)(col)     + e1 * (float)(col + 1)
                 + e2 * (float)(col + 2) + e3 * (float)(col + 3);
        float pv = (e0 + e1 + e2 + e3) * (float)row;
        float ps = e0 * w4.x + e1 * w4.y + e2 * w4.z + e3 * w4.w;

        pu = wave_sum(pu);
        pv = wave_sum(pv);
        ps = wave_sum(ps);
        __syncthreads();
        if (lane == 0) { red[wave] = pu; red[4 + wave] = pv; red[8 + wave] = ps; }
        __syncthreads();
        if (t == 0) {
            const int blk = b * L + hp * NP + wp;
            out[blk * 2 + 0]       = red[0] + red[1] + red[2]  + red[3];
            out[blk * 2 + 1]       = red[4] + red[5] + red[6]  + red[7];
            out[2 * (8 * L) + blk] = red[8] + red[9] + red[10] + red[11];
        }
    }

    // ---------- publish att, then wait for the strip's 16 patches ----------
    __threadfence();                 // each thread's attws stores -> device scope
    __syncthreads();                 // all threads fenced before the signal
    if (t == 0) {
        __hip_atomic_fetch_add(&flags[s], 1u, __ATOMIC_RELEASE,
                               __HIP_MEMORY_SCOPE_AGENT);
        while (__hip_atomic_load(&flags[s], __ATOMIC_ACQUIRE,
                                 __HIP_MEMORY_SCOPE_AGENT) < 16u) {
            __builtin_amdgcn_s_sleep(2);
        }
    }
    __syncthreads();                 // whole block proceeds after acquire

    // ---------- Phase B: stream 8 channel strips against the att strip ----------
    const int ch = cg * 8 + wave * 2;
    const unsigned short* ap = attws + ((size_t)b * W512 + hp * PATCH) * W512 + lane * 4;
    const float* dp0 = desc + (((size_t)(b * NCH + ch)) * W512 + hp * PATCH) * W512 + lane * 4;
    const float* dp1 = dp0 + PLANE;

    float a00 = 0.f, a01 = 0.f, a10 = 0.f, a11 = 0.f;
    #pragma unroll 4
    for (int r = 0; r < PATCH; ++r) {
        const int off = r * W512;
        const u16x4 uv0 = *(const u16x4*)(ap + off);
        const u16x4 uv1 = *(const u16x4*)(ap + off + 256);
        const f32x4 d00 = __builtin_nontemporal_load((const f32x4*)(dp0 + off));
        const f32x4 d01 = __builtin_nontemporal_load((const f32x4*)(dp0 + off + 256));
        const f32x4 d10 = __builtin_nontemporal_load((const f32x4*)(dp1 + off));
        const f32x4 d11 = __builtin_nontemporal_load((const f32x4*)(dp1 + off + 256));
        const float ax0 = bf2f(uv0.x), ay0 = bf2f(uv0.y),
                    az0 = bf2f(uv0.z), aw0 = bf2f(uv0.w);
        const float ax1 = bf2f(uv1.x), ay1 = bf2f(uv1.y),
                    az1 = bf2f(uv1.z), aw1 = bf2f(uv1.w);
        a00 += ax0 * d00.x + ay0 * d00.y + az0 * d00.z + aw0 * d00.w;
        a01 += ax1 * d01.x + ay1 * d01.y + az1 * d01.z + aw1 * d01.w;
        a10 += ax0 * d10.x + ay0 * d10.y + az0 * d10.z + aw0 * d10.w;
        a11 += ax1 * d11.x + ay1 * d11.y + az1 * d11.z + aw1 * d11.w;
    }

    #pragma unroll
    for (int o = 1; o <= 4; o <<= 1) {
        a00 += __shfl_xor(a00, o, 64);
        a01 += __shfl_xor(a01, o, 64);
        a10 += __shfl_xor(a10, o, 64);
        a11 += __shfl_xor(a11, o, 64);
    }

    if ((lane & 7) == 0) {
        const int wp0 = lane >> 3;
        float* outd = out + 4096 + 2048;
        float* o0 = outd + ((size_t)(b * NCH + ch)) * L + hp * NP;
        o0[wp0]     = a00;
        o0[8 + wp0] = a01;
        float* o1 = o0 + L;
        o1[wp0]     = a10;
        o1[8 + wp0] = a11;
    }
}

extern "C" void kernel_launch(void* const* d_in, const int* in_sizes, int n_in,
                              void* d_out, int out_size, void* d_ws, size_t ws_size,
                              hipStream_t stream) {
    const float* det  = (const float*)d_in[0];
    const float* wsc  = (const float*)d_in[1];
    const float* desc = (const float*)d_in[2];
    float* out = (float*)d_out;

    unsigned short* attws = (unsigned short*)d_ws;                  // 4 MiB bf16 att map
    unsigned int*   flags = (unsigned int*)((char*)d_ws + (4 << 20)); // 128 counters

    hipMemsetAsync(flags, 0, NSTRIP * sizeof(unsigned int), stream);
    fused_kernel<<<dim3(2048), dim3(256), 0, stream>>>(det, wsc, desc, out, attws, flags);
}

// Round 6
// 171.506 us; speedup vs baseline: 2.2937x; 2.2937x over previous
//
#include <hip/hip_runtime.h>
#include <hip/hip_bf16.h>

#define W512   512
#define PATCH  32
#define NP     16        // patches per side
#define L      256       // patches per image
#define NCH    128       // descriptor channels
#define PLANE  (W512 * W512)

typedef float  f32x4 __attribute__((ext_vector_type(4)));
typedef unsigned short u16x4 __attribute__((ext_vector_type(4)));

__device__ __forceinline__ unsigned short f2bf(float f) {
    __hip_bfloat16 h = __float2bfloat16(f);
    return *reinterpret_cast<unsigned short*>(&h);
}
__device__ __forceinline__ float bf2f(unsigned short u) {
    return __uint_as_float(((unsigned int)u) << 16);
}

__device__ __forceinline__ float wave_max(float v) {
    #pragma unroll
    for (int o = 32; o; o >>= 1) v = fmaxf(v, __shfl_xor(v, o, 64));
    return v;
}
__device__ __forceinline__ float wave_sum(float v) {
    #pragma unroll
    for (int o = 32; o; o >>= 1) v += __shfl_xor(v, o, 64);
    return v;
}

// ---------------- kernel 1: softmax att + coords + scores ----------------
__global__ __launch_bounds__(256)
void att_kernel(const float* __restrict__ det,
                const float* __restrict__ wsc,
                float* __restrict__ out,
                unsigned short* __restrict__ attws) {
    __shared__ float red[12];

    const int blk = blockIdx.x;       // b*L + l
    const int b   = blk >> 8;
    const int l   = blk & 255;
    const int hp  = l >> 4;
    const int wp  = l & 15;

    const int t    = threadIdx.x;
    const int wave = t >> 6;
    const int lane = t & 63;
    const int r    = t >> 3;          // row within patch
    const int q    = t & 7;           // float4 index within row

    const int row = hp * PATCH + r;
    const int col = wp * PATCH + q * 4;
    const size_t pix = (size_t)b * PLANE + (size_t)row * W512 + col;

    const f32x4 d4 = __builtin_nontemporal_load((const f32x4*)(det + pix));

    float m = fmaxf(fmaxf(d4.x, d4.y), fmaxf(d4.z, d4.w));
    m = wave_max(m);
    if (lane == 0) red[wave] = m;
    __syncthreads();
    m = fmaxf(fmaxf(red[0], red[1]), fmaxf(red[2], red[3]));

    float e0 = expf(d4.x - m);
    float e1 = expf(d4.y - m);
    float e2 = expf(d4.z - m);
    float e3 = expf(d4.w - m);

    float s = wave_sum(e0 + e1 + e2 + e3);
    if (lane == 0) red[4 + wave] = s;
    __syncthreads();
    s = red[4] + red[5] + red[6] + red[7];
    const float inv = 1.0f / s;
    e0 *= inv; e1 *= inv; e2 *= inv; e3 *= inv;

    // normalized attention, bf16, image layout (same indexing as det)
    u16x4 pk;
    pk.x = f2bf(e0); pk.y = f2bf(e1); pk.z = f2bf(e2); pk.w = f2bf(e3);
    *(u16x4*)(attws + pix) = pk;

    const f32x4 w4 = __builtin_nontemporal_load((const f32x4*)(wsc + pix));
    float pu = e0 * (float)(col)     + e1 * (float)(col + 1)
             + e2 * (float)(col + 2) + e3 * (float)(col + 3);
    float pv = (e0 + e1 + e2 + e3) * (float)row;
    float ps = e0 * w4.x + e1 * w4.y + e2 * w4.z + e3 * w4.w;

    pu = wave_sum(pu);
    pv = wave_sum(pv);
    ps = wave_sum(ps);
    __syncthreads();
    if (lane == 0) { red[wave] = pu; red[4 + wave] = pv; red[8 + wave] = ps; }
    __syncthreads();
    if (t == 0) {
        out[blk * 2 + 0]       = red[0] + red[1] + red[2]  + red[3];
        out[blk * 2 + 1]       = red[4] + red[5] + red[6]  + red[7];
        out[2 * (8 * L) + blk] = red[8] + red[9] + red[10] + red[11];
    }
}

// ---------------- kernel 2: strip-sequential descriptor pooling ----------------
// block = one (b, hp, channel-group-of-8); wave owns 2 channels and streams
// the strip's contiguous 64 KiB region of each plane (nt: zero reuse).
__global__ __launch_bounds__(256)
void pool_kernel(const float* __restrict__ desc,
                 const unsigned short* __restrict__ attws,
                 float* __restrict__ outd) {
    const int bid   = blockIdx.x;     // cg in high bits -> same-strip blocks
    const int cg    = bid >> 7;       //   co-locate per XCD (bid%8)
    const int strip = bid & 127;      // b*16 + hp
    const int b     = strip >> 4;
    const int hp    = strip & 15;

    const int t    = threadIdx.x;
    const int wave = t >> 6;
    const int lane = t & 63;
    const int ch   = cg * 8 + wave * 2;

    const unsigned short* ap = attws + ((size_t)b * W512 + hp * PATCH) * W512 + lane * 4;
    const float* dp0 = desc + (((size_t)(b * NCH + ch)) * W512 + hp * PATCH) * W512 + lane * 4;
    const float* dp1 = dp0 + PLANE;

    float a00 = 0.f, a01 = 0.f, a10 = 0.f, a11 = 0.f;
    #pragma unroll 4
    for (int r = 0; r < PATCH; ++r) {
        const int off = r * W512;
        const u16x4 uv0 = *(const u16x4*)(ap + off);
        const u16x4 uv1 = *(const u16x4*)(ap + off + 256);
        const f32x4 d00 = __builtin_nontemporal_load((const f32x4*)(dp0 + off));
        const f32x4 d01 = __builtin_nontemporal_load((const f32x4*)(dp0 + off + 256));
        const f32x4 d10 = __builtin_nontemporal_load((const f32x4*)(dp1 + off));
        const f32x4 d11 = __builtin_nontemporal_load((const f32x4*)(dp1 + off + 256));
        const float ax0 = bf2f(uv0.x), ay0 = bf2f(uv0.y),
                    az0 = bf2f(uv0.z), aw0 = bf2f(uv0.w);
        const float ax1 = bf2f(uv1.x), ay1 = bf2f(uv1.y),
                    az1 = bf2f(uv1.z), aw1 = bf2f(uv1.w);
        a00 += ax0 * d00.x + ay0 * d00.y + az0 * d00.z + aw0 * d00.w;
        a01 += ax1 * d01.x + ay1 * d01.y + az1 * d01.z + aw1 * d01.w;
        a10 += ax0 * d10.x + ay0 * d10.y + az0 * d10.z + aw0 * d10.w;
        a11 += ax1 * d11.x + ay1 * d11.y + az1 * d11.z + aw1 * d11.w;
    }

    #pragma unroll
    for (int o = 1; o <= 4; o <<= 1) {
        a00 += __shfl_xor(a00, o, 64);
        a01 += __shfl_xor(a01, o, 64);
        a10 += __shfl_xor(a10, o, 64);
        a11 += __shfl_xor(a11, o, 64);
    }

    if ((lane & 7) == 0) {
        const int wp0 = lane >> 3;
        float* o0 = outd + ((size_t)(b * NCH + ch)) * L + hp * NP;
        o0[wp0]     = a00;
        o0[8 + wp0] = a01;
        float* o1 = o0 + L;
        o1[wp0]     = a10;
        o1[8 + wp0] = a11;
    }
}

extern "C" void kernel_launch(void* const* d_in, const int* in_sizes, int n_in,
                              void* d_out, int out_size, void* d_ws, size_t ws_size,
                              hipStream_t stream) {
    const float* det  = (const float*)d_in[0];
    const float* wsc  = (const float*)d_in[1];
    const float* desc = (const float*)d_in[2];
    float* out = (float*)d_out;
    unsigned short* attws = (unsigned short*)d_ws;   // 4 MiB bf16 attention map

    att_kernel<<<dim3(8 * L), dim3(256), 0, stream>>>(det, wsc, out, attws);
    pool_kernel<<<dim3(2048), dim3(256), 0, stream>>>(desc, attws, out + 4096 + 2048);
}